// Round 1
// baseline (406.125 us; speedup 1.0000x reference)
//
#include <hip/hip_runtime.h>
#include <math.h>

#define B_ 4
#define T_ 4096
#define C_ 1024
#define H_ 64
#define ROWS_ (B_*T_)

// ---------------------------------------------------------------------------
// Kernel 1: fused QKV projection. Block = 256 threads handles 64 rows.
// LDS-staged x tile [64][64] (stride 68) and weight tile [64][192] (stride 196)
// to avoid 16-way bank conflicts. Register tile 4 rows x 12 cols per thread.
// ---------------------------------------------------------------------------
__global__ __launch_bounds__(256) void qkv_proj_kernel(
    const float* __restrict__ x,  const float* __restrict__ wq,
    const float* __restrict__ wk, const float* __restrict__ wv,
    float* __restrict__ q, float* __restrict__ k, float* __restrict__ v)
{
    __shared__ float xs[64][68];     // x tile, padded stride
    __shared__ float ws[64][196];    // [c][3*64] weight tile, padded stride

    const int tid = threadIdx.x;
    const int rb  = blockIdx.x * 64;
    const int tr  = tid >> 4;        // 0..15
    const int tc  = tid & 15;        // 0..15

    float acc[4][12];
    #pragma unroll
    for (int i = 0; i < 4; ++i)
        #pragma unroll
        for (int j = 0; j < 12; ++j) acc[i][j] = 0.f;

    for (int ck = 0; ck < C_/64; ++ck) {
        const int c0 = ck * 64;
        // stage x tile: 64 rows x 64 cols, 4 float4 per thread
        #pragma unroll
        for (int i = 0; i < 4; ++i) {
            const int r = i*16 + tr;
            const float4 xv = *reinterpret_cast<const float4*>(
                &x[(size_t)(rb + r)*C_ + c0 + tc*4]);
            *reinterpret_cast<float4*>(&xs[r][tc*4]) = xv;
        }
        // stage weight tiles: 3 matrices, [64 c][64 h] each
        const float* wms[3] = {wq, wk, wv};
        #pragma unroll
        for (int m = 0; m < 3; ++m) {
            #pragma unroll
            for (int i = 0; i < 4; ++i) {
                const int r = i*16 + tr;
                const float4 wv4 = *reinterpret_cast<const float4*>(
                    &wms[m][(size_t)(c0 + r)*H_ + tc*4]);
                *reinterpret_cast<float4*>(&ws[r][m*64 + tc*4]) = wv4;
            }
        }
        __syncthreads();
        #pragma unroll 4
        for (int c = 0; c < 64; ++c) {
            float xv[4];
            #pragma unroll
            for (int i = 0; i < 4; ++i) xv[i] = xs[i*16 + tr][c];
            float wvv[12];
            #pragma unroll
            for (int j = 0; j < 6; ++j) {
                const float2 t2 = *reinterpret_cast<const float2*>(&ws[c][tc*12 + 2*j]);
                wvv[2*j] = t2.x; wvv[2*j+1] = t2.y;
            }
            #pragma unroll
            for (int i = 0; i < 4; ++i)
                #pragma unroll
                for (int j = 0; j < 12; ++j)
                    acc[i][j] = fmaf(xv[i], wvv[j], acc[i][j]);
        }
        __syncthreads();
    }

    // epilogue: scatter to q/k/v
    #pragma unroll
    for (int i = 0; i < 4; ++i) {
        const int row = rb + i*16 + tr;
        #pragma unroll
        for (int j = 0; j < 12; ++j) {
            const int col = tc*12 + j;
            const int m   = col >> 6;
            const int h   = col & 63;
            float* dst = (m == 0) ? q : (m == 1) ? k : v;
            dst[(size_t)row*H_ + h] = acc[i][j];
        }
    }
}

// ---------------------------------------------------------------------------
// Kernel 2: RoPE on q and k in-place. One thread per (row, pair).
// Matches ref: inv_freq = theta^(-2i/H); ang = t * inv_freq (fp32 mul);
// precise sincosf (default libm, proper arg reduction).
// ---------------------------------------------------------------------------
__global__ __launch_bounds__(256) void rope_kernel(float* __restrict__ q,
                                                   float* __restrict__ k)
{
    int idx = blockIdx.x * 256 + threadIdx.x;        // over 2 * ROWS * 32
    const int npairs = ROWS_ * (H_/2);
    float* ptr = q;
    if (idx >= npairs) { idx -= npairs; ptr = k; }
    const int row = idx >> 5;
    const int i   = idx & 31;
    const int t   = row & (T_-1);
    const float inv = powf(10000.0f, -(float)(2*i) / (float)H_);
    const float ang = (float)t * inv;
    float sn, cs;
    sincosf(ang, &sn, &cs);
    float2 ab = *reinterpret_cast<float2*>(&ptr[(size_t)row*H_ + 2*i]);
    float2 o;
    o.x = ab.x*cs - ab.y*sn;
    o.y = ab.x*sn + ab.y*cs;
    *reinterpret_cast<float2*>(&ptr[(size_t)row*H_ + 2*i]) = o;
}

// ---------------------------------------------------------------------------
// Kernel 3: causal flash attention, fp32. BQ=32 queries per block, BK=64.
// 256 threads: thread (tq=tid>>4, tk=tid&15) owns S rows {tq,tq+16} x
// cols {tk+16j}. Online softmax with width-16 shfl_xor reduction (lanes
// with equal tq are the low-4-bit tk group - xor masks stay in-group).
// Zig-zag qt mapping pairs long+short blocks per CU for causal balance.
// ---------------------------------------------------------------------------
__global__ __launch_bounds__(256) void flash_attn_kernel(
    const float* __restrict__ q, const float* __restrict__ k,
    const float* __restrict__ v, float* __restrict__ out)
{
    __shared__ float Qs[32][68];
    __shared__ float Ks[64][68];
    __shared__ float Vs[64][68];
    __shared__ float Ps[32][68];

    const int tid = threadIdx.x;
    const int bx  = blockIdx.x;
    const int b   = bx & 3;
    const int rr  = bx >> 2;                         // 0..127
    const int qt  = (rr < 64) ? (2*rr) : (2*(127 - rr) + 1);  // balance pairing
    const int q0  = qt * 32;
    const size_t base = (size_t)b * T_ * H_;

    const int tq = tid >> 4;                          // 0..15
    const int tk = tid & 15;                          // 0..15

    // stage Q tile (32x64)
    {
        const int r = tid >> 3;                       // 0..31
        const int c = (tid & 7) * 8;
        *reinterpret_cast<float4*>(&Qs[r][c]) =
            *reinterpret_cast<const float4*>(&q[base + (size_t)(q0 + r)*H_ + c]);
        *reinterpret_cast<float4*>(&Qs[r][c+4]) =
            *reinterpret_cast<const float4*>(&q[base + (size_t)(q0 + r)*H_ + c + 4]);
    }

    float m[2] = {-1e30f, -1e30f};
    float l[2] = {0.f, 0.f};
    float4 acc[2];
    acc[0] = make_float4(0.f,0.f,0.f,0.f);
    acc[1] = make_float4(0.f,0.f,0.f,0.f);

    const int ktmax = (q0 + 31) >> 6;
    for (int kt = 0; kt <= ktmax; ++kt) {
        __syncthreads();     // prev-iter PV done reading Ks/Vs/Ps (also covers Q stage)
        // stage K,V tiles (64x64 each): 4 float4 per thread per matrix
        {
            const int r  = tid >> 2;                  // 0..63
            const int cb = (tid & 3) * 16;
            #pragma unroll
            for (int i = 0; i < 4; ++i) {
                *reinterpret_cast<float4*>(&Ks[r][cb + 4*i]) =
                    *reinterpret_cast<const float4*>(&k[base + (size_t)(kt*64 + r)*H_ + cb + 4*i]);
                *reinterpret_cast<float4*>(&Vs[r][cb + 4*i]) =
                    *reinterpret_cast<const float4*>(&v[base + (size_t)(kt*64 + r)*H_ + cb + 4*i]);
            }
        }
        __syncthreads();

        // S = (Q K^T) * 0.125, register tile 2x4
        float s[2][4] = {{0,0,0,0},{0,0,0,0}};
        #pragma unroll 4
        for (int c4 = 0; c4 < 16; ++c4) {
            const float4 q0v = *reinterpret_cast<const float4*>(&Qs[tq   ][c4*4]);
            const float4 q1v = *reinterpret_cast<const float4*>(&Qs[tq+16][c4*4]);
            #pragma unroll
            for (int j = 0; j < 4; ++j) {
                const float4 kv = *reinterpret_cast<const float4*>(&Ks[tk + 16*j][c4*4]);
                s[0][j] = fmaf(q0v.x, kv.x, fmaf(q0v.y, kv.y,
                          fmaf(q0v.z, kv.z, fmaf(q0v.w, kv.w, s[0][j]))));
                s[1][j] = fmaf(q1v.x, kv.x, fmaf(q1v.y, kv.y,
                          fmaf(q1v.z, kv.z, fmaf(q1v.w, kv.w, s[1][j]))));
            }
        }
        // causal mask + scale
        #pragma unroll
        for (int i = 0; i < 2; ++i)
            #pragma unroll
            for (int j = 0; j < 4; ++j) {
                const int gq = q0 + tq + 16*i;
                const int gk = kt*64 + tk + 16*j;
                s[i][j] = (gk <= gq) ? s[i][j] * 0.125f : -1e30f;
            }

        // online softmax
        float p[2][4], scl[2];
        #pragma unroll
        for (int i = 0; i < 2; ++i) {
            float mx = fmaxf(fmaxf(s[i][0], s[i][1]), fmaxf(s[i][2], s[i][3]));
            #pragma unroll
            for (int off = 1; off < 16; off <<= 1)
                mx = fmaxf(mx, __shfl_xor(mx, off));
            const float mn = fmaxf(m[i], mx);
            scl[i] = __expf(m[i] - mn);
            float ls = 0.f;
            #pragma unroll
            for (int j = 0; j < 4; ++j) { p[i][j] = __expf(s[i][j] - mn); ls += p[i][j]; }
            #pragma unroll
            for (int off = 1; off < 16; off <<= 1)
                ls += __shfl_xor(ls, off);
            l[i] = l[i]*scl[i] + ls;
            m[i] = mn;
        }
        // stage P, rescale O
        #pragma unroll
        for (int i = 0; i < 2; ++i)
            #pragma unroll
            for (int j = 0; j < 4; ++j)
                Ps[tq + 16*i][tk + 16*j] = p[i][j];
        acc[0].x *= scl[0]; acc[0].y *= scl[0]; acc[0].z *= scl[0]; acc[0].w *= scl[0];
        acc[1].x *= scl[1]; acc[1].y *= scl[1]; acc[1].z *= scl[1]; acc[1].w *= scl[1];
        __syncthreads();

        // O += P V : thread owns rows {tq,tq+16} x h-block tk*4..+3
        #pragma unroll 8
        for (int kk = 0; kk < 64; ++kk) {
            const float4 vv = *reinterpret_cast<const float4*>(&Vs[kk][tk*4]);
            const float p0 = Ps[tq   ][kk];
            const float p1 = Ps[tq+16][kk];
            acc[0].x = fmaf(p0, vv.x, acc[0].x);
            acc[0].y = fmaf(p0, vv.y, acc[0].y);
            acc[0].z = fmaf(p0, vv.z, acc[0].z);
            acc[0].w = fmaf(p0, vv.w, acc[0].w);
            acc[1].x = fmaf(p1, vv.x, acc[1].x);
            acc[1].y = fmaf(p1, vv.y, acc[1].y);
            acc[1].z = fmaf(p1, vv.z, acc[1].z);
            acc[1].w = fmaf(p1, vv.w, acc[1].w);
        }
    }

    // finalize: O /= l, write out
    const float i0 = 1.f / l[0];
    const float i1 = 1.f / l[1];
    float4 o0 = make_float4(acc[0].x*i0, acc[0].y*i0, acc[0].z*i0, acc[0].w*i0);
    float4 o1 = make_float4(acc[1].x*i1, acc[1].y*i1, acc[1].z*i1, acc[1].w*i1);
    *reinterpret_cast<float4*>(&out[base + (size_t)(q0 + tq   )*H_ + tk*4]) = o0;
    *reinterpret_cast<float4*>(&out[base + (size_t)(q0 + tq+16)*H_ + tk*4]) = o1;
}

// ---------------------------------------------------------------------------
extern "C" void kernel_launch(void* const* d_in, const int* in_sizes, int n_in,
                              void* d_out, int out_size, void* d_ws, size_t ws_size,
                              hipStream_t stream) {
    const float* x  = (const float*)d_in[0];
    const float* wq = (const float*)d_in[1];
    const float* wk = (const float*)d_in[2];
    const float* wv = (const float*)d_in[3];
    float* out = (float*)d_out;

    float* qw = (float*)d_ws;                         // ROWS_*H_ floats
    float* kw = qw + (size_t)ROWS_ * H_;
    float* vw = kw + (size_t)ROWS_ * H_;

    qkv_proj_kernel<<<ROWS_/64, 256, 0, stream>>>(x, wq, wk, wv, qw, kw, vw);
    rope_kernel<<<(2*ROWS_*(H_/2))/256, 256, 0, stream>>>(qw, kw);
    flash_attn_kernel<<<(T_/32)*B_, 256, 0, stream>>>(qw, kw, vw, out);
}

// Round 2
// 214.375 us; speedup vs baseline: 1.8945x; 1.8945x over previous
//
#include <hip/hip_runtime.h>
#include <math.h>

#define B_ 4
#define T_ 4096
#define C_ 1024
#define H_ 64
#define ROWS_ (B_*T_)

typedef __attribute__((ext_vector_type(8))) short bf16x8;
typedef __attribute__((ext_vector_type(4))) float f32x4;

__device__ __forceinline__ unsigned short f2bf(float f) {
    union { float f; unsigned u; } x; x.f = f;
    unsigned r = x.u + 0x7fffu + ((x.u >> 16) & 1u);   // RNE
    return (unsigned short)(r >> 16);
}

// ---------------------------------------------------------------------------
// Kernel 1: fused QKV projection (fp32 compute) + RoPE + bf16 emit.
// q,k -> bf16 [row][64] after RoPE; v -> bf16 transposed vT[b*64+h][4096].
// ---------------------------------------------------------------------------
__global__ __launch_bounds__(256) void qkv_proj_kernel(
    const float* __restrict__ x,  const float* __restrict__ wq,
    const float* __restrict__ wk, const float* __restrict__ wv,
    unsigned short* __restrict__ qb, unsigned short* __restrict__ kb,
    unsigned short* __restrict__ vtb)
{
    __shared__ float xs[64][68];
    __shared__ float ws[64][196];

    const int tid = threadIdx.x;
    const int rb  = blockIdx.x * 64;
    const int tr  = tid >> 4;
    const int tc  = tid & 15;

    float acc[4][12];
    #pragma unroll
    for (int i = 0; i < 4; ++i)
        #pragma unroll
        for (int j = 0; j < 12; ++j) acc[i][j] = 0.f;

    for (int ck = 0; ck < C_/64; ++ck) {
        const int c0 = ck * 64;
        #pragma unroll
        for (int i = 0; i < 4; ++i) {
            const int r = i*16 + tr;
            *reinterpret_cast<float4*>(&xs[r][tc*4]) =
                *reinterpret_cast<const float4*>(&x[(size_t)(rb + r)*C_ + c0 + tc*4]);
        }
        const float* wms[3] = {wq, wk, wv};
        #pragma unroll
        for (int m = 0; m < 3; ++m) {
            #pragma unroll
            for (int i = 0; i < 4; ++i) {
                const int r = i*16 + tr;
                *reinterpret_cast<float4*>(&ws[r][m*64 + tc*4]) =
                    *reinterpret_cast<const float4*>(&wms[m][(size_t)(c0 + r)*H_ + tc*4]);
            }
        }
        __syncthreads();
        #pragma unroll 4
        for (int c = 0; c < 64; ++c) {
            float xv[4];
            #pragma unroll
            for (int i = 0; i < 4; ++i) xv[i] = xs[i*16 + tr][c];
            float wvv[12];
            #pragma unroll
            for (int j = 0; j < 6; ++j) {
                const float2 t2 = *reinterpret_cast<const float2*>(&ws[c][tc*12 + 2*j]);
                wvv[2*j] = t2.x; wvv[2*j+1] = t2.y;
            }
            #pragma unroll
            for (int i = 0; i < 4; ++i)
                #pragma unroll
                for (int j = 0; j < 12; ++j)
                    acc[i][j] = fmaf(xv[i], wvv[j], acc[i][j]);
        }
        __syncthreads();
    }

    // epilogue: RoPE + bf16 emit
    #pragma unroll
    for (int i = 0; i < 4; ++i) {
        const int row = rb + i*16 + tr;
        const int t   = row & (T_-1);
        const int bb  = row >> 12;
        #pragma unroll
        for (int j = 0; j < 12; j += 2) {
            const int col = tc*12 + j;
            const int m   = col >> 6;
            const int h   = col & 63;
            const float a = acc[i][j], b2 = acc[i][j+1];
            if (m < 2) {
                const float inv = powf(10000.0f, -(float)h / 64.0f);
                float sn, cs;
                sincosf((float)t * inv, &sn, &cs);
                const float oa = a*cs - b2*sn;
                const float ob = a*sn + b2*cs;
                const unsigned pk = (unsigned)f2bf(oa) | ((unsigned)f2bf(ob) << 16);
                unsigned short* dst = (m == 0) ? qb : kb;
                *reinterpret_cast<unsigned*>(&dst[(size_t)row*H_ + h]) = pk;
            } else {
                vtb[((size_t)(bb*64 + h    ))*T_ + t] = f2bf(a);
                vtb[((size_t)(bb*64 + h + 1))*T_ + t] = f2bf(b2);
            }
        }
    }
}

// ---------------------------------------------------------------------------
// Kernel 2: bf16 MFMA causal flash attention.
// 256 blocks x 8 waves. BQ=64 (wave sub owns 16 q-rows), BK=64.
// Split-K: waves 0-3 even k-tiles, waves 4-7 odd; LDS flash-combine at end.
// Swapped QK^T: mfma(A=K, B=Q) -> S^T, lane owns one q-row (q = lane&15),
// softmax reduce = 2 shfl_xor (16,32). All LDS tiles XOR-swizzled
// byte ^= ((row&7)<<4) (row stride 128B => would be 16-way conflict).
// ---------------------------------------------------------------------------
__global__ __launch_bounds__(512) void attn_kernel(
    const unsigned short* __restrict__ qb, const unsigned short* __restrict__ kb,
    const unsigned short* __restrict__ vtb, float* __restrict__ out)
{
    __shared__ unsigned short Kls[2][4096];   // [group][64 rows][64 bf16] swizzled
    __shared__ unsigned short Vls[2][4096];   // [group][64 h][64 t] swizzled
    __shared__ unsigned short Pls[8][1024];   // per-wave 16x64 bf16 swizzled
    __shared__ float part_m[64];
    __shared__ float part_l[64];
    __shared__ float part_o[64][68];

    const int tid  = threadIdx.x;
    const int w    = tid >> 6;       // wave 0..7
    const int lane = tid & 63;
    const int g    = w >> 2;         // k-split group
    const int sub  = w & 3;          // q sub-tile within block
    const int b    = blockIdx.x & 3;
    const int qt   = 63 - (blockIdx.x >> 2);
    const int q0   = qt * 64;
    const size_t rbase = (size_t)b * T_;

    const int lr = lane & 15;
    const int lg = lane >> 4;

    char* Kb = (char*)&Kls[g][0];
    char* Vb = (char*)&Vls[g][0];
    char* Pw = (char*)&Pls[w][0];

    // Q fragments (B-operand layout: col=lane&15 -> q-row, k=(lane>>4)*8+j -> d)
    bf16x8 qf[2];
    {
        const unsigned short* qp = qb + (rbase + q0 + sub*16 + lr)*H_ + lg*8;
        qf[0] = *reinterpret_cast<const bf16x8*>(qp);
        qf[1] = *reinterpret_cast<const bf16x8*>(qp + 32);
    }

    float mrow = -1e30f, lrow = 0.f;
    f32x4 acc[4];
    #pragma unroll
    for (int hs = 0; hs < 4; ++hs) acc[hs] = f32x4{0.f, 0.f, 0.f, 0.f};

    const int ntk = qt + 1;
    const int nit = (ntk + 1) >> 1;

    // staging geometry: this wave stages slots s=0,1; 8 rows per slot
    const int srow = (lane >> 3);              // 0..7 within slot
    const int scol = (lane & 7) * 8;           // bf16 elems (16B)

    uint4 kst[2], vst[2];
    auto issue_loads = [&](int kt) {
        #pragma unroll
        for (int s = 0; s < 2; ++s) {
            const int r = (s*4 + sub)*8 + srow;          // tile row 0..63
            kst[s] = *reinterpret_cast<const uint4*>(
                &kb[(rbase + (size_t)kt*64 + r)*H_ + scol]);
            vst[s] = *reinterpret_cast<const uint4*>(
                &vtb[((size_t)(b*64 + r))*T_ + (size_t)kt*64 + scol]);
        }
    };
    auto write_lds = [&]() {
        #pragma unroll
        for (int s = 0; s < 2; ++s) {
            const int r   = (s*4 + sub)*8 + srow;
            const int off = r*128 + ((scol*2) ^ ((r & 7) << 4));
            *reinterpret_cast<uint4*>(Kb + off) = kst[s];
            *reinterpret_cast<uint4*>(Vb + off) = vst[s];
        }
    };

    // prologue: load this group's first tile (kt = g), if any
    bool have = (g < ntk);
    if (have) issue_loads(g);

    for (int it = 0; it < nit; ++it) {
        const int kt     = 2*it + g;
        const bool active = (kt < ntk);
        const int ktn     = kt + 2;
        const bool nact   = (ktn < ntk);

        __syncthreads();                 // prev-iter LDS reads done
        if (active) write_lds();
        __syncthreads();                 // tiles visible
        if (nact) issue_loads(ktn);      // overlap next loads with compute

        if (active) {
            // ---- S^T = K Q^T (two mfma per 16-wide k-subtile) ----
            f32x4 st[4];
            #pragma unroll
            for (int ks = 0; ks < 4; ++ks) {
                const int r  = ks*16 + lr;
                const int sw = (r & 7) << 4;
                bf16x8 kf0 = *reinterpret_cast<const bf16x8*>(Kb + r*128 + ((lg*16     ) ^ sw));
                bf16x8 kf1 = *reinterpret_cast<const bf16x8*>(Kb + r*128 + ((lg*16 + 64) ^ sw));
                f32x4 t = {0.f, 0.f, 0.f, 0.f};
                t = __builtin_amdgcn_mfma_f32_16x16x32_bf16(kf0, qf[0], t, 0, 0, 0);
                t = __builtin_amdgcn_mfma_f32_16x16x32_bf16(kf1, qf[1], t, 0, 0, 0);
                st[ks] = t;
            }
            // ---- mask + scale + online softmax (lane owns q-row q0+sub*16+lr) ----
            const int qg = q0 + sub*16 + lr;
            float mx = -1e30f;
            #pragma unroll
            for (int ks = 0; ks < 4; ++ks)
                #pragma unroll
                for (int i = 0; i < 4; ++i) {
                    const int kg = kt*64 + ks*16 + lg*4 + i;
                    const float v = (kg <= qg) ? st[ks][i]*0.125f : -1e30f;
                    st[ks][i] = v;
                    mx = fmaxf(mx, v);
                }
            mx = fmaxf(mx, __shfl_xor(mx, 16));
            mx = fmaxf(mx, __shfl_xor(mx, 32));
            const float mn  = fmaxf(mrow, mx);
            const float scl = __expf(mrow - mn);
            float ls = 0.f;
            #pragma unroll
            for (int ks = 0; ks < 4; ++ks)
                #pragma unroll
                for (int i = 0; i < 4; ++i) {
                    const float p = __expf(st[ks][i] - mn);
                    st[ks][i] = p;
                    ls += p;
                }
            ls += __shfl_xor(ls, 16);
            ls += __shfl_xor(ls, 32);
            lrow = lrow*scl + ls;
            mrow = mn;

            // ---- P -> bf16 -> per-wave LDS (A-operand layout transpose) ----
            const int swp = (lr & 7) << 4;
            #pragma unroll
            for (int ks = 0; ks < 4; ++ks) {
                const unsigned u0 = (unsigned)f2bf(st[ks][0]) | ((unsigned)f2bf(st[ks][1]) << 16);
                const unsigned u1 = (unsigned)f2bf(st[ks][2]) | ((unsigned)f2bf(st[ks][3]) << 16);
                *reinterpret_cast<uint2*>(Pw + lr*128 + ((ks*32 + lg*8) ^ swp)) =
                    make_uint2(u0, u1);
            }

            // ---- rescale O (acc rows are q'=(lane>>4)*4+i -> shuffle scl) ----
            float sclr[4];
            #pragma unroll
            for (int i = 0; i < 4; ++i) sclr[i] = __shfl(scl, lg*4 + i);
            #pragma unroll
            for (int hs = 0; hs < 4; ++hs)
                #pragma unroll
                for (int i = 0; i < 4; ++i) acc[hs][i] *= sclr[i];

            // ---- O += P V ----
            bf16x8 pf0 = *reinterpret_cast<const bf16x8*>(Pw + lr*128 + ((lg*16     ) ^ swp));
            bf16x8 pf1 = *reinterpret_cast<const bf16x8*>(Pw + lr*128 + ((lg*16 + 64) ^ swp));
            #pragma unroll
            for (int hs = 0; hs < 4; ++hs) {
                const int rv  = hs*16 + lr;
                const int swv = (rv & 7) << 4;
                bf16x8 vf0 = *reinterpret_cast<const bf16x8*>(Vb + rv*128 + ((lg*16     ) ^ swv));
                bf16x8 vf1 = *reinterpret_cast<const bf16x8*>(Vb + rv*128 + ((lg*16 + 64) ^ swv));
                acc[hs] = __builtin_amdgcn_mfma_f32_16x16x32_bf16(pf0, vf0, acc[hs], 0, 0, 0);
                acc[hs] = __builtin_amdgcn_mfma_f32_16x16x32_bf16(pf1, vf1, acc[hs], 0, 0, 0);
            }
        }
    }

    // ---- split-K combine ----
    float m_r[4], l_r[4];
    #pragma unroll
    for (int i = 0; i < 4; ++i) {
        m_r[i] = __shfl(mrow, lg*4 + i);
        l_r[i] = __shfl(lrow, lg*4 + i);
    }
    if (g == 1) {
        #pragma unroll
        for (int i = 0; i < 4; ++i) {
            const int qr = sub*16 + lg*4 + i;
            part_m[qr] = m_r[i];
            part_l[qr] = l_r[i];
            #pragma unroll
            for (int hs = 0; hs < 4; ++hs)
                part_o[qr][hs*16 + lr] = acc[hs][i];
        }
    }
    __syncthreads();
    if (g == 0) {
        #pragma unroll
        for (int i = 0; i < 4; ++i) {
            const int qr = sub*16 + lg*4 + i;
            const float m1 = part_m[qr], l1 = part_l[qr];
            const float M  = fmaxf(m_r[i], m1);
            const float a0 = __expf(m_r[i] - M);
            const float a1 = __expf(m1 - M);
            const float L  = l_r[i]*a0 + l1*a1;
            const float iv = 1.f / L;
            #pragma unroll
            for (int hs = 0; hs < 4; ++hs) {
                const float o = (acc[hs][i]*a0 + part_o[qr][hs*16 + lr]*a1) * iv;
                out[(rbase + q0 + qr)*H_ + hs*16 + lr] = o;
            }
        }
    }
}

// ---------------------------------------------------------------------------
extern "C" void kernel_launch(void* const* d_in, const int* in_sizes, int n_in,
                              void* d_out, int out_size, void* d_ws, size_t ws_size,
                              hipStream_t stream) {
    const float* x  = (const float*)d_in[0];
    const float* wq = (const float*)d_in[1];
    const float* wk = (const float*)d_in[2];
    const float* wv = (const float*)d_in[3];
    float* out = (float*)d_out;

    unsigned short* qb  = (unsigned short*)d_ws;                   // 1M bf16
    unsigned short* kb  = qb + (size_t)ROWS_ * H_;
    unsigned short* vtb = kb + (size_t)ROWS_ * H_;                 // [b*64+h][T]

    qkv_proj_kernel<<<ROWS_/64, 256, 0, stream>>>(x, wq, wk, wv, qb, kb, vtb);
    attn_kernel<<<(T_/64)*B_, 512, 0, stream>>>(qb, kb, vtb, out);
}

// Round 3
// 163.194 us; speedup vs baseline: 2.4886x; 1.3136x over previous
//
#include <hip/hip_runtime.h>
#include <math.h>

#define B_ 4
#define T_ 4096
#define C_ 1024
#define H_ 64
#define ROWS_ (B_*T_)

typedef __attribute__((ext_vector_type(8))) short bf16x8;
typedef __attribute__((ext_vector_type(4))) float f32x4;

__device__ __forceinline__ unsigned short f2bf(float f) {
    union { float f; unsigned u; } x; x.f = f;
    unsigned r = x.u + 0x7fffu + ((x.u >> 16) & 1u);   // RNE
    return (unsigned short)(r >> 16);
}

// ---------------------------------------------------------------------------
// Kernel 0: weight prep. w[1024 k][64 n] fp32 -> wt[m][64 n][1024 k] bf16
// (transposed, k-contiguous) so the GEMM B-operand stages coalesced.
// ---------------------------------------------------------------------------
__global__ __launch_bounds__(256) void prep_weights(
    const float* __restrict__ wq, const float* __restrict__ wk,
    const float* __restrict__ wv, unsigned short* __restrict__ wt)
{
    __shared__ float ts[64][68];
    const int m  = blockIdx.x >> 4;          // 0..2
    const int k0 = (blockIdx.x & 15) * 64;
    const float* w = (m == 0) ? wq : (m == 1) ? wk : wv;
    const int tid = threadIdx.x;
    {
        const int r = tid >> 2;              // k row 0..63
        const int c = (tid & 3) * 16;        // n col
        #pragma unroll
        for (int i = 0; i < 4; ++i)
            *reinterpret_cast<float4*>(&ts[r][c + 4*i]) =
                *reinterpret_cast<const float4*>(&w[(size_t)(k0 + r)*H_ + c + 4*i]);
    }
    __syncthreads();
    {
        const int n  = tid >> 2;             // 0..63
        const int kc = (tid & 3) * 16;       // 0..63
        unsigned short outp[16];
        #pragma unroll
        for (int j = 0; j < 16; ++j) outp[j] = f2bf(ts[kc + j][n]);
        unsigned short* dst = &wt[((size_t)m*64 + n)*C_ + k0 + kc];
        *reinterpret_cast<uint4*>(dst)     = *reinterpret_cast<uint4*>(&outp[0]);
        *reinterpret_cast<uint4*>(dst + 8) = *reinterpret_cast<uint4*>(&outp[8]);
    }
}

// ---------------------------------------------------------------------------
// Kernel 1: bf16 MFMA QKV projection + fused RoPE + bf16/V^T emit.
// Grid 256 (BM=64 rows), 512 threads = 8 waves (4 row-tiles x 2 col-halves),
// BN=192 (q|k|v), BK=64. LDS tiles XOR-swizzled; next-step global loads
// issued before current compute (reg prefetch) to keep HBM saturated.
// ---------------------------------------------------------------------------
__global__ __launch_bounds__(512) void qkv_mfma_kernel(
    const float* __restrict__ x, const unsigned short* __restrict__ wt,
    unsigned short* __restrict__ qb, unsigned short* __restrict__ kb,
    unsigned short* __restrict__ vtb)
{
    __shared__ unsigned short As[64*64];     // [row][k] swizzled, 128B rows
    __shared__ unsigned short Ws[192*64];    // [n][k]  swizzled, 128B rows

    const int tid  = threadIdx.x;
    const int w    = tid >> 6;
    const int lane = tid & 63;
    const int rt   = w >> 1;                 // row-tile 0..3
    const int ch   = w & 1;                  // col-half 0..1
    const int lr   = lane & 15;
    const int lg   = lane >> 4;
    const int rb   = blockIdx.x * 64;

    // staging geometry
    const int ar = tid >> 3;                 // x row 0..63
    const int ac = (tid & 7) * 8;            // x k-elem 0..56

    float4 axr[2];
    uint4  wvr[3];

    auto load_A = [&](int t) {
        const float* p = &x[(size_t)(rb + ar)*C_ + t*64 + ac];
        axr[0] = *reinterpret_cast<const float4*>(p);
        axr[1] = *reinterpret_cast<const float4*>(p + 4);
    };
    auto load_W = [&](int t) {
        #pragma unroll
        for (int s = 0; s < 3; ++s) {
            const int slot = s*512 + tid;
            const int r    = slot >> 3;      // n-row 0..191
            const int c8   = (slot & 7) * 8; // k elem
            wvr[s] = *reinterpret_cast<const uint4*>(&wt[(size_t)r*C_ + t*64 + c8]);
        }
    };
    auto write_A = [&]() {
        unsigned short tmp[8];
        #pragma unroll
        for (int i = 0; i < 4; ++i) {
            tmp[i]     = f2bf(((const float*)&axr[0])[i]);
            tmp[4 + i] = f2bf(((const float*)&axr[1])[i]);
        }
        const int off = ar*128 + ((ac*2) ^ ((ar & 7) << 4));
        *reinterpret_cast<uint4*>((char*)As + off) = *reinterpret_cast<uint4*>(tmp);
    };
    auto write_W = [&]() {
        #pragma unroll
        for (int s = 0; s < 3; ++s) {
            const int slot = s*512 + tid;
            const int r    = slot >> 3;
            const int cb   = (slot & 7) * 16;
            *reinterpret_cast<uint4*>((char*)Ws + r*128 + (cb ^ ((r & 7) << 4))) = wvr[s];
        }
    };

    f32x4 acc[6];
    #pragma unroll
    for (int j = 0; j < 6; ++j) acc[j] = f32x4{0.f, 0.f, 0.f, 0.f};

    load_A(0); load_W(0);
    for (int t = 0; t < 16; ++t) {
        __syncthreads();                     // LDS consumers of step t-1 done
        write_A(); write_W();
        __syncthreads();                     // tiles visible
        if (t < 15) { load_A(t + 1); load_W(t + 1); }   // in flight over compute
        #pragma unroll
        for (int kh = 0; kh < 2; ++kh) {
            const int arow = rt*16 + lr;
            bf16x8 af = *reinterpret_cast<const bf16x8*>(
                (char*)As + arow*128 + ((kh*64 + lg*16) ^ ((arow & 7) << 4)));
            #pragma unroll
            for (int j = 0; j < 6; ++j) {
                const int n = ch*96 + j*16 + lr;
                bf16x8 bf = *reinterpret_cast<const bf16x8*>(
                    (char*)Ws + n*128 + ((kh*64 + lg*16) ^ ((n & 7) << 4)));
                acc[j] = __builtin_amdgcn_mfma_f32_16x16x32_bf16(af, bf, acc[j], 0, 0, 0);
            }
        }
    }

    // epilogue: C row = rb + rt*16 + lg*4 + i, col = ch*96 + j*16 + lr
    const int row0 = rb + rt*16 + lg*4;
    #pragma unroll
    for (int j = 0; j < 6; ++j) {
        const int c = ch*96 + j*16 + lr;     // 0..191
        const int m = c >> 6;
        const int h = c & 63;
        if (m < 2) {
            // RoPE pair: even/odd cols sit in adjacent lanes
            const float inv = powf(10000.0f, -(float)(h & ~1) / 64.0f);
            unsigned short* dst = (m == 0) ? qb : kb;
            #pragma unroll
            for (int i = 0; i < 4; ++i) {
                const float v  = acc[j][i];
                const float pr = __shfl_xor(v, 1);
                const int  r   = row0 + i;
                const int  tp  = r & (T_ - 1);
                float sn, cs;
                sincosf((float)tp * inv, &sn, &cs);
                if (!(h & 1)) {
                    const float oe = v*cs - pr*sn;   // even elem
                    const float oo = v*sn + pr*cs;   // odd elem
                    const unsigned pk = (unsigned)f2bf(oe) | ((unsigned)f2bf(oo) << 16);
                    *reinterpret_cast<unsigned*>(&dst[(size_t)r*H_ + h]) = pk;
                }
            }
        } else {
            // V^T: lane owns 4 consecutive t at fixed h -> one 8B store
            const int bh = (row0 >> 12)*64 + h;
            const int tp = row0 & (T_ - 1);
            unsigned short pk[4];
            #pragma unroll
            for (int i = 0; i < 4; ++i) pk[i] = f2bf(acc[j][i]);
            *reinterpret_cast<uint2*>(&vtb[(size_t)bh*T_ + tp]) =
                *reinterpret_cast<uint2*>(pk);
        }
    }
}

// ---------------------------------------------------------------------------
// Kernel 2: bf16 MFMA causal flash attention (unchanged from round 2).
// ---------------------------------------------------------------------------
__global__ __launch_bounds__(512) void attn_kernel(
    const unsigned short* __restrict__ qb, const unsigned short* __restrict__ kb,
    const unsigned short* __restrict__ vtb, float* __restrict__ out)
{
    __shared__ unsigned short Kls[2][4096];
    __shared__ unsigned short Vls[2][4096];
    __shared__ unsigned short Pls[8][1024];
    __shared__ float part_m[64];
    __shared__ float part_l[64];
    __shared__ float part_o[64][68];

    const int tid  = threadIdx.x;
    const int w    = tid >> 6;
    const int lane = tid & 63;
    const int g    = w >> 2;
    const int sub  = w & 3;
    const int b    = blockIdx.x & 3;
    const int qt   = 63 - (blockIdx.x >> 2);
    const int q0   = qt * 64;
    const size_t rbase = (size_t)b * T_;

    const int lr = lane & 15;
    const int lg = lane >> 4;

    char* Kb = (char*)&Kls[g][0];
    char* Vb = (char*)&Vls[g][0];
    char* Pw = (char*)&Pls[w][0];

    bf16x8 qf[2];
    {
        const unsigned short* qp = qb + (rbase + q0 + sub*16 + lr)*H_ + lg*8;
        qf[0] = *reinterpret_cast<const bf16x8*>(qp);
        qf[1] = *reinterpret_cast<const bf16x8*>(qp + 32);
    }

    float mrow = -1e30f, lrow = 0.f;
    f32x4 acc[4];
    #pragma unroll
    for (int hs = 0; hs < 4; ++hs) acc[hs] = f32x4{0.f, 0.f, 0.f, 0.f};

    const int ntk = qt + 1;
    const int nit = (ntk + 1) >> 1;

    const int srow = (lane >> 3);
    const int scol = (lane & 7) * 8;

    uint4 kst[2], vst[2];
    auto issue_loads = [&](int kt) {
        #pragma unroll
        for (int s = 0; s < 2; ++s) {
            const int r = (s*4 + sub)*8 + srow;
            kst[s] = *reinterpret_cast<const uint4*>(
                &kb[(rbase + (size_t)kt*64 + r)*H_ + scol]);
            vst[s] = *reinterpret_cast<const uint4*>(
                &vtb[((size_t)(b*64 + r))*T_ + (size_t)kt*64 + scol]);
        }
    };
    auto write_lds = [&]() {
        #pragma unroll
        for (int s = 0; s < 2; ++s) {
            const int r   = (s*4 + sub)*8 + srow;
            const int off = r*128 + ((scol*2) ^ ((r & 7) << 4));
            *reinterpret_cast<uint4*>(Kb + off) = kst[s];
            *reinterpret_cast<uint4*>(Vb + off) = vst[s];
        }
    };

    bool have = (g < ntk);
    if (have) issue_loads(g);

    for (int it = 0; it < nit; ++it) {
        const int kt      = 2*it + g;
        const bool active = (kt < ntk);
        const int ktn     = kt + 2;
        const bool nact   = (ktn < ntk);

        __syncthreads();
        if (active) write_lds();
        __syncthreads();
        if (nact) issue_loads(ktn);

        if (active) {
            f32x4 st[4];
            #pragma unroll
            for (int ks = 0; ks < 4; ++ks) {
                const int r  = ks*16 + lr;
                const int sw = (r & 7) << 4;
                bf16x8 kf0 = *reinterpret_cast<const bf16x8*>(Kb + r*128 + ((lg*16     ) ^ sw));
                bf16x8 kf1 = *reinterpret_cast<const bf16x8*>(Kb + r*128 + ((lg*16 + 64) ^ sw));
                f32x4 t = {0.f, 0.f, 0.f, 0.f};
                t = __builtin_amdgcn_mfma_f32_16x16x32_bf16(kf0, qf[0], t, 0, 0, 0);
                t = __builtin_amdgcn_mfma_f32_16x16x32_bf16(kf1, qf[1], t, 0, 0, 0);
                st[ks] = t;
            }
            const int qg = q0 + sub*16 + lr;
            float mx = -1e30f;
            #pragma unroll
            for (int ks = 0; ks < 4; ++ks)
                #pragma unroll
                for (int i = 0; i < 4; ++i) {
                    const int kg = kt*64 + ks*16 + lg*4 + i;
                    const float v = (kg <= qg) ? st[ks][i]*0.125f : -1e30f;
                    st[ks][i] = v;
                    mx = fmaxf(mx, v);
                }
            mx = fmaxf(mx, __shfl_xor(mx, 16));
            mx = fmaxf(mx, __shfl_xor(mx, 32));
            const float mn  = fmaxf(mrow, mx);
            const float scl = __expf(mrow - mn);
            float ls = 0.f;
            #pragma unroll
            for (int ks = 0; ks < 4; ++ks)
                #pragma unroll
                for (int i = 0; i < 4; ++i) {
                    const float p = __expf(st[ks][i] - mn);
                    st[ks][i] = p;
                    ls += p;
                }
            ls += __shfl_xor(ls, 16);
            ls += __shfl_xor(ls, 32);
            lrow = lrow*scl + ls;
            mrow = mn;

            const int swp = (lr & 7) << 4;
            #pragma unroll
            for (int ks = 0; ks < 4; ++ks) {
                const unsigned u0 = (unsigned)f2bf(st[ks][0]) | ((unsigned)f2bf(st[ks][1]) << 16);
                const unsigned u1 = (unsigned)f2bf(st[ks][2]) | ((unsigned)f2bf(st[ks][3]) << 16);
                *reinterpret_cast<uint2*>(Pw + lr*128 + ((ks*32 + lg*8) ^ swp)) =
                    make_uint2(u0, u1);
            }

            float sclr[4];
            #pragma unroll
            for (int i = 0; i < 4; ++i) sclr[i] = __shfl(scl, lg*4 + i);
            #pragma unroll
            for (int hs = 0; hs < 4; ++hs)
                #pragma unroll
                for (int i = 0; i < 4; ++i) acc[hs][i] *= sclr[i];

            bf16x8 pf0 = *reinterpret_cast<const bf16x8*>(Pw + lr*128 + ((lg*16     ) ^ swp));
            bf16x8 pf1 = *reinterpret_cast<const bf16x8*>(Pw + lr*128 + ((lg*16 + 64) ^ swp));
            #pragma unroll
            for (int hs = 0; hs < 4; ++hs) {
                const int rv  = hs*16 + lr;
                const int swv = (rv & 7) << 4;
                bf16x8 vf0 = *reinterpret_cast<const bf16x8*>(Vb + rv*128 + ((lg*16     ) ^ swv));
                bf16x8 vf1 = *reinterpret_cast<const bf16x8*>(Vb + rv*128 + ((lg*16 + 64) ^ swv));
                acc[hs] = __builtin_amdgcn_mfma_f32_16x16x32_bf16(pf0, vf0, acc[hs], 0, 0, 0);
                acc[hs] = __builtin_amdgcn_mfma_f32_16x16x32_bf16(pf1, vf1, acc[hs], 0, 0, 0);
            }
        }
    }

    float m_r[4], l_r[4];
    #pragma unroll
    for (int i = 0; i < 4; ++i) {
        m_r[i] = __shfl(mrow, lg*4 + i);
        l_r[i] = __shfl(lrow, lg*4 + i);
    }
    if (g == 1) {
        #pragma unroll
        for (int i = 0; i < 4; ++i) {
            const int qr = sub*16 + lg*4 + i;
            part_m[qr] = m_r[i];
            part_l[qr] = l_r[i];
            #pragma unroll
            for (int hs = 0; hs < 4; ++hs)
                part_o[qr][hs*16 + lr] = acc[hs][i];
        }
    }
    __syncthreads();
    if (g == 0) {
        #pragma unroll
        for (int i = 0; i < 4; ++i) {
            const int qr = sub*16 + lg*4 + i;
            const float m1 = part_m[qr], l1 = part_l[qr];
            const float M  = fmaxf(m_r[i], m1);
            const float a0 = __expf(m_r[i] - M);
            const float a1 = __expf(m1 - M);
            const float L  = l_r[i]*a0 + l1*a1;
            const float iv = 1.f / L;
            #pragma unroll
            for (int hs = 0; hs < 4; ++hs) {
                const float o = (acc[hs][i]*a0 + part_o[qr][hs*16 + lr]*a1) * iv;
                out[(rbase + q0 + qr)*H_ + hs*16 + lr] = o;
            }
        }
    }
}

// ---------------------------------------------------------------------------
extern "C" void kernel_launch(void* const* d_in, const int* in_sizes, int n_in,
                              void* d_out, int out_size, void* d_ws, size_t ws_size,
                              hipStream_t stream) {
    const float* x  = (const float*)d_in[0];
    const float* wq = (const float*)d_in[1];
    const float* wk = (const float*)d_in[2];
    const float* wv = (const float*)d_in[3];
    float* out = (float*)d_out;

    unsigned short* qb  = (unsigned short*)d_ws;                   // 1M bf16
    unsigned short* kb  = qb  + (size_t)ROWS_ * H_;
    unsigned short* vtb = kb  + (size_t)ROWS_ * H_;                // [b*64+h][T]
    unsigned short* wt  = vtb + (size_t)ROWS_ * H_;                // [3][64][1024]

    prep_weights<<<48, 256, 0, stream>>>(wq, wk, wv, wt);
    qkv_mfma_kernel<<<ROWS_/64, 512, 0, stream>>>(x, wt, qb, kb, vtb);
    attn_kernel<<<(T_/64)*B_, 512, 0, stream>>>(qb, kb, vtb, out);
}

// Round 4
// 124.301 us; speedup vs baseline: 3.2673x; 1.3129x over previous
//
#include <hip/hip_runtime.h>
#include <math.h>

#define B_ 4
#define T_ 4096
#define C_ 1024
#define H_ 64
#define ROWS_ (B_*T_)

typedef __attribute__((ext_vector_type(8))) short bf16x8;
typedef __attribute__((ext_vector_type(4))) float f32x4;

__device__ __forceinline__ unsigned short f2bf(float f) {
    union { float f; unsigned u; } x; x.f = f;
    unsigned r = x.u + 0x7fffu + ((x.u >> 16) & 1u);   // RNE
    return (unsigned short)(r >> 16);
}
__device__ __forceinline__ float bf2f(unsigned short s) {
    union { unsigned u; float f; } x; x.u = ((unsigned)s) << 16;
    return x.f;
}

// ---------------------------------------------------------------------------
// Kernel 0: weight prep. w[1024 k][64 n] fp32 -> wt[m][64 n][1024 k] bf16.
// ---------------------------------------------------------------------------
__global__ __launch_bounds__(256) void prep_weights(
    const float* __restrict__ wq, const float* __restrict__ wk,
    const float* __restrict__ wv, unsigned short* __restrict__ wt)
{
    __shared__ float ts[64][68];
    const int m  = blockIdx.x >> 4;
    const int k0 = (blockIdx.x & 15) * 64;
    const float* w = (m == 0) ? wq : (m == 1) ? wk : wv;
    const int tid = threadIdx.x;
    {
        const int r = tid >> 2;
        const int c = (tid & 3) * 16;
        #pragma unroll
        for (int i = 0; i < 4; ++i)
            *reinterpret_cast<float4*>(&ts[r][c + 4*i]) =
                *reinterpret_cast<const float4*>(&w[(size_t)(k0 + r)*H_ + c + 4*i]);
    }
    __syncthreads();
    {
        const int n  = tid >> 2;
        const int kc = (tid & 3) * 16;
        unsigned short outp[16];
        #pragma unroll
        for (int j = 0; j < 16; ++j) outp[j] = f2bf(ts[kc + j][n]);
        unsigned short* dst = &wt[((size_t)m*64 + n)*C_ + k0 + kc];
        *reinterpret_cast<uint4*>(dst)     = *reinterpret_cast<uint4*>(&outp[0]);
        *reinterpret_cast<uint4*>(dst + 8) = *reinterpret_cast<uint4*>(&outp[8]);
    }
}

// ---------------------------------------------------------------------------
// Kernel 1: bf16 MFMA QKV projection + fused RoPE + bf16/V^T emit.
// (unchanged from round 3)
// ---------------------------------------------------------------------------
__global__ __launch_bounds__(512) void qkv_mfma_kernel(
    const float* __restrict__ x, const unsigned short* __restrict__ wt,
    unsigned short* __restrict__ qb, unsigned short* __restrict__ kb,
    unsigned short* __restrict__ vtb)
{
    __shared__ unsigned short As[64*64];
    __shared__ unsigned short Ws[192*64];

    const int tid  = threadIdx.x;
    const int w    = tid >> 6;
    const int lane = tid & 63;
    const int rt   = w >> 1;
    const int ch   = w & 1;
    const int lr   = lane & 15;
    const int lg   = lane >> 4;
    const int rb   = blockIdx.x * 64;

    const int ar = tid >> 3;
    const int ac = (tid & 7) * 8;

    float4 axr[2];
    uint4  wvr[3];

    auto load_A = [&](int t) {
        const float* p = &x[(size_t)(rb + ar)*C_ + t*64 + ac];
        axr[0] = *reinterpret_cast<const float4*>(p);
        axr[1] = *reinterpret_cast<const float4*>(p + 4);
    };
    auto load_W = [&](int t) {
        #pragma unroll
        for (int s = 0; s < 3; ++s) {
            const int slot = s*512 + tid;
            const int r    = slot >> 3;
            const int c8   = (slot & 7) * 8;
            wvr[s] = *reinterpret_cast<const uint4*>(&wt[(size_t)r*C_ + t*64 + c8]);
        }
    };
    auto write_A = [&]() {
        unsigned short tmp[8];
        #pragma unroll
        for (int i = 0; i < 4; ++i) {
            tmp[i]     = f2bf(((const float*)&axr[0])[i]);
            tmp[4 + i] = f2bf(((const float*)&axr[1])[i]);
        }
        const int off = ar*128 + ((ac*2) ^ ((ar & 7) << 4));
        *reinterpret_cast<uint4*>((char*)As + off) = *reinterpret_cast<uint4*>(tmp);
    };
    auto write_W = [&]() {
        #pragma unroll
        for (int s = 0; s < 3; ++s) {
            const int slot = s*512 + tid;
            const int r    = slot >> 3;
            const int cb   = (slot & 7) * 16;
            *reinterpret_cast<uint4*>((char*)Ws + r*128 + (cb ^ ((r & 7) << 4))) = wvr[s];
        }
    };

    f32x4 acc[6];
    #pragma unroll
    for (int j = 0; j < 6; ++j) acc[j] = f32x4{0.f, 0.f, 0.f, 0.f};

    load_A(0); load_W(0);
    for (int t = 0; t < 16; ++t) {
        __syncthreads();
        write_A(); write_W();
        __syncthreads();
        if (t < 15) { load_A(t + 1); load_W(t + 1); }
        #pragma unroll
        for (int kh = 0; kh < 2; ++kh) {
            const int arow = rt*16 + lr;
            bf16x8 af = *reinterpret_cast<const bf16x8*>(
                (char*)As + arow*128 + ((kh*64 + lg*16) ^ ((arow & 7) << 4)));
            #pragma unroll
            for (int j = 0; j < 6; ++j) {
                const int n = ch*96 + j*16 + lr;
                bf16x8 bf = *reinterpret_cast<const bf16x8*>(
                    (char*)Ws + n*128 + ((kh*64 + lg*16) ^ ((n & 7) << 4)));
                acc[j] = __builtin_amdgcn_mfma_f32_16x16x32_bf16(af, bf, acc[j], 0, 0, 0);
            }
        }
    }

    const int row0 = rb + rt*16 + lg*4;
    #pragma unroll
    for (int j = 0; j < 6; ++j) {
        const int c = ch*96 + j*16 + lr;
        const int m = c >> 6;
        const int h = c & 63;
        if (m < 2) {
            const float inv = powf(10000.0f, -(float)(h & ~1) / 64.0f);
            unsigned short* dst = (m == 0) ? qb : kb;
            #pragma unroll
            for (int i = 0; i < 4; ++i) {
                const float v  = acc[j][i];
                const float pr = __shfl_xor(v, 1);
                const int  r   = row0 + i;
                const int  tp  = r & (T_ - 1);
                float sn, cs;
                sincosf((float)tp * inv, &sn, &cs);
                if (!(h & 1)) {
                    const float oe = v*cs - pr*sn;
                    const float oo = v*sn + pr*cs;
                    const unsigned pk = (unsigned)f2bf(oe) | ((unsigned)f2bf(oo) << 16);
                    *reinterpret_cast<unsigned*>(&dst[(size_t)r*H_ + h]) = pk;
                }
            }
        } else {
            const int bh = (row0 >> 12)*64 + h;
            const int tp = row0 & (T_ - 1);
            unsigned short pk[4];
            #pragma unroll
            for (int i = 0; i < 4; ++i) pk[i] = f2bf(acc[j][i]);
            *reinterpret_cast<uint2*>(&vtb[(size_t)bh*T_ + tp]) =
                *reinterpret_cast<uint2*>(pk);
        }
    }
}

// ---------------------------------------------------------------------------
// Kernel 2: uniform-chunk split-K flash attention.
// Work unit = (b, q-tile of 64 rows, chunk of up to 16 k-tiles). 640 blocks
// of 4 waves (256 thr), LDS 40KB -> 4 blocks/CU resident. Double-buffered
// K/V (one barrier per step). Emits un-normalized partial (m,l fp32; O bf16).
// Chunk layout per batch: qt in [0,16): 1 chunk; [16,32): 2; [32,48): 3;
// [48,64): 4 -> 160 chunks/batch, flat id = cid = blockIdx.x.
// ---------------------------------------------------------------------------
__global__ __launch_bounds__(256) void attn_chunk_kernel(
    const unsigned short* __restrict__ qb, const unsigned short* __restrict__ kb,
    const unsigned short* __restrict__ vtb,
    unsigned short* __restrict__ partO, float* __restrict__ partML)
{
    __shared__ unsigned short Kls[2][4096];
    __shared__ unsigned short Vls[2][4096];
    __shared__ unsigned short Pls[4][1024];

    const int tid  = threadIdx.x;
    const int w    = tid >> 6;       // wave 0..3, owns q-rows w*16..+15
    const int lane = tid & 63;
    const int lr   = lane & 15;
    const int lg   = lane >> 4;

    const int cid = blockIdx.x;      // 0..639
    const int b   = cid / 160;
    const int r0  = cid - b*160;
    int qt, c;
    if      (r0 < 16) { qt = r0;               c = 0;           }
    else if (r0 < 48) { qt = 16 + (r0-16)/2;   c = (r0-16) & 1; }
    else if (r0 < 96) { qt = 32 + (r0-48)/3;   c = (r0-48) % 3; }
    else              { qt = 48 + (r0-96)/4;   c = (r0-96) & 3; }

    const int q0  = qt * 64;
    const size_t rbase = (size_t)b * T_;
    const int kt0 = c * 16;
    const int ns  = min(kt0 + 16, qt + 1) - kt0;

    char* Pw = (char*)&Pls[w][0];

    // Q fragment (B-operand: col=lane&15 -> q-row, k=(lane>>4)*8+j -> d)
    bf16x8 qf[2];
    {
        const unsigned short* qp = qb + (rbase + q0 + w*16 + lr)*H_ + lg*8;
        qf[0] = *reinterpret_cast<const bf16x8*>(qp);
        qf[1] = *reinterpret_cast<const bf16x8*>(qp + 32);
    }

    float mrow = -1e30f, lrow = 0.f;
    f32x4 acc[4];
    #pragma unroll
    for (int hs = 0; hs < 4; ++hs) acc[hs] = f32x4{0.f, 0.f, 0.f, 0.f};

    // staging: 256 threads, each 2x16B per matrix (rows tid>>3 and 32+tid>>3)
    const int srow = tid >> 3;           // 0..31
    const int scol = (tid & 7) * 8;      // bf16 elems
    uint4 kst[2], vst[2];
    auto issue_loads = [&](int kt) {
        #pragma unroll
        for (int s = 0; s < 2; ++s) {
            const int r = s*32 + srow;
            kst[s] = *reinterpret_cast<const uint4*>(
                &kb[(rbase + (size_t)kt*64 + r)*H_ + scol]);
            vst[s] = *reinterpret_cast<const uint4*>(
                &vtb[((size_t)(b*64 + r))*T_ + (size_t)kt*64 + scol]);
        }
    };
    auto write_lds = [&](int buf) {
        #pragma unroll
        for (int s = 0; s < 2; ++s) {
            const int r   = s*32 + srow;
            const int off = r*128 + ((scol*2) ^ ((r & 7) << 4));
            *reinterpret_cast<uint4*>((char*)&Kls[buf][0] + off) = kst[s];
            *reinterpret_cast<uint4*>((char*)&Vls[buf][0] + off) = vst[s];
        }
    };

    issue_loads(kt0);
    write_lds(0);

    for (int s = 0; s < ns; ++s) {
        __syncthreads();                       // buffer s&1 visible
        if (s + 1 < ns) issue_loads(kt0 + s + 1);
        const int kt = kt0 + s;
        char* Kb = (char*)&Kls[s & 1][0];
        char* Vb = (char*)&Vls[s & 1][0];

        // S^T = K Q^T
        f32x4 st[4];
        #pragma unroll
        for (int ks = 0; ks < 4; ++ks) {
            const int rr2 = ks*16 + lr;
            const int sw  = (rr2 & 7) << 4;
            bf16x8 kf0 = *reinterpret_cast<const bf16x8*>(Kb + rr2*128 + ((lg*16     ) ^ sw));
            bf16x8 kf1 = *reinterpret_cast<const bf16x8*>(Kb + rr2*128 + ((lg*16 + 64) ^ sw));
            f32x4 t = {0.f, 0.f, 0.f, 0.f};
            t = __builtin_amdgcn_mfma_f32_16x16x32_bf16(kf0, qf[0], t, 0, 0, 0);
            t = __builtin_amdgcn_mfma_f32_16x16x32_bf16(kf1, qf[1], t, 0, 0, 0);
            st[ks] = t;
        }

        // mask + scale + online softmax (lane owns q-row q0 + w*16 + lr)
        const int qg = q0 + w*16 + lr;
        float mx = -1e30f;
        #pragma unroll
        for (int ks = 0; ks < 4; ++ks)
            #pragma unroll
            for (int i = 0; i < 4; ++i) {
                const int kg = kt*64 + ks*16 + lg*4 + i;
                const float v = (kg <= qg) ? st[ks][i]*0.125f : -1e30f;
                st[ks][i] = v;
                mx = fmaxf(mx, v);
            }
        mx = fmaxf(mx, __shfl_xor(mx, 16));
        mx = fmaxf(mx, __shfl_xor(mx, 32));
        const float mn  = fmaxf(mrow, mx);
        const float scl = __expf(mrow - mn);
        float ls = 0.f;
        #pragma unroll
        for (int ks = 0; ks < 4; ++ks)
            #pragma unroll
            for (int i = 0; i < 4; ++i) {
                const float p = __expf(st[ks][i] - mn);
                st[ks][i] = p;
                ls += p;
            }
        ls += __shfl_xor(ls, 16);
        ls += __shfl_xor(ls, 32);
        lrow = lrow*scl + ls;
        mrow = mn;

        // P -> bf16 -> per-wave LDS (A-operand transpose)
        const int swp = (lr & 7) << 4;
        #pragma unroll
        for (int ks = 0; ks < 4; ++ks) {
            const unsigned u0 = (unsigned)f2bf(st[ks][0]) | ((unsigned)f2bf(st[ks][1]) << 16);
            const unsigned u1 = (unsigned)f2bf(st[ks][2]) | ((unsigned)f2bf(st[ks][3]) << 16);
            *reinterpret_cast<uint2*>(Pw + lr*128 + ((ks*32 + lg*8) ^ swp)) =
                make_uint2(u0, u1);
        }

        // rescale O
        float sclr[4];
        #pragma unroll
        for (int i = 0; i < 4; ++i) sclr[i] = __shfl(scl, lg*4 + i);
        #pragma unroll
        for (int hs = 0; hs < 4; ++hs)
            #pragma unroll
            for (int i = 0; i < 4; ++i) acc[hs][i] *= sclr[i];

        // O += P V
        bf16x8 pf0 = *reinterpret_cast<const bf16x8*>(Pw + lr*128 + ((lg*16     ) ^ swp));
        bf16x8 pf1 = *reinterpret_cast<const bf16x8*>(Pw + lr*128 + ((lg*16 + 64) ^ swp));
        #pragma unroll
        for (int hs = 0; hs < 4; ++hs) {
            const int rv  = hs*16 + lr;
            const int swv = (rv & 7) << 4;
            bf16x8 vf0 = *reinterpret_cast<const bf16x8*>(Vb + rv*128 + ((lg*16     ) ^ swv));
            bf16x8 vf1 = *reinterpret_cast<const bf16x8*>(Vb + rv*128 + ((lg*16 + 64) ^ swv));
            acc[hs] = __builtin_amdgcn_mfma_f32_16x16x32_bf16(pf0, vf0, acc[hs], 0, 0, 0);
            acc[hs] = __builtin_amdgcn_mfma_f32_16x16x32_bf16(pf1, vf1, acc[hs], 0, 0, 0);
        }

        if (s + 1 < ns) write_lds((s + 1) & 1);
    }

    // write partial: m,l (fp32) + un-normalized O (bf16)
    const int myrow = w*16 + lr;
    if (lg == 0) {
        partML[(size_t)cid*128 + myrow]      = mrow;
        partML[(size_t)cid*128 + 64 + myrow] = lrow;
    }
    #pragma unroll
    for (int hs = 0; hs < 4; ++hs)
        #pragma unroll
        for (int i = 0; i < 4; ++i)
            partO[(size_t)cid*4096 + (size_t)(w*16 + lg*4 + i)*64 + hs*16 + lr] =
                f2bf(acc[hs][i]);
}

// ---------------------------------------------------------------------------
// Kernel 3: combine partials per (b, q-tile). 256 blocks x 256 threads;
// thread handles one row x 16 h.
// ---------------------------------------------------------------------------
__global__ __launch_bounds__(256) void combine_kernel(
    const unsigned short* __restrict__ partO, const float* __restrict__ partML,
    float* __restrict__ out)
{
    const int bq   = blockIdx.x;       // 0..255
    const int b    = bq >> 6;
    const int qt   = bq & 63;
    const int full = qt >> 4;
    const int nc   = full + 1;
    const int base = 16*((full*(full+1)) >> 1) + (qt & 15)*(full + 1);
    const int cb   = b*160 + base;

    const int tid = threadIdx.x;
    const int row = tid >> 2;
    const int h0  = (tid & 3) * 16;

    float mi[4], wi[4];
    float M = -1e30f;
    #pragma unroll
    for (int i = 0; i < 4; ++i) if (i < nc) {
        mi[i] = partML[(size_t)(cb + i)*128 + row];
        M = fmaxf(M, mi[i]);
    }
    float L = 0.f;
    #pragma unroll
    for (int i = 0; i < 4; ++i) if (i < nc) {
        wi[i] = __expf(mi[i] - M);
        L += partML[(size_t)(cb + i)*128 + 64 + row] * wi[i];
    }
    const float inv = 1.f / L;

    float o[16];
    #pragma unroll
    for (int j = 0; j < 16; ++j) o[j] = 0.f;
    #pragma unroll
    for (int i = 0; i < 4; ++i) if (i < nc) {
        const unsigned short* p = &partO[(size_t)(cb + i)*4096 + (size_t)row*64 + h0];
        uint4 u0 = *reinterpret_cast<const uint4*>(p);
        uint4 u1 = *reinterpret_cast<const uint4*>(p + 8);
        const unsigned* uu = (const unsigned*)&u0;
        #pragma unroll
        for (int j = 0; j < 4; ++j) {
            o[2*j]   += bf2f((unsigned short)(uu[j] & 0xffffu)) * wi[i];
            o[2*j+1] += bf2f((unsigned short)(uu[j] >> 16))     * wi[i];
        }
        const unsigned* uv = (const unsigned*)&u1;
        #pragma unroll
        for (int j = 0; j < 4; ++j) {
            o[8+2*j]   += bf2f((unsigned short)(uv[j] & 0xffffu)) * wi[i];
            o[8+2*j+1] += bf2f((unsigned short)(uv[j] >> 16))     * wi[i];
        }
    }
    float* op = &out[((size_t)b*T_ + (size_t)qt*64 + row)*H_ + h0];
    #pragma unroll
    for (int j = 0; j < 4; ++j) {
        float4 v = make_float4(o[4*j]*inv, o[4*j+1]*inv, o[4*j+2]*inv, o[4*j+3]*inv);
        *reinterpret_cast<float4*>(op + 4*j) = v;
    }
}

// ---------------------------------------------------------------------------
extern "C" void kernel_launch(void* const* d_in, const int* in_sizes, int n_in,
                              void* d_out, int out_size, void* d_ws, size_t ws_size,
                              hipStream_t stream) {
    const float* x  = (const float*)d_in[0];
    const float* wq = (const float*)d_in[1];
    const float* wk = (const float*)d_in[2];
    const float* wv = (const float*)d_in[3];
    float* out = (float*)d_out;

    unsigned short* qb    = (unsigned short*)d_ws;                 // 2MB
    unsigned short* kb    = qb  + (size_t)ROWS_ * H_;              // 2MB
    unsigned short* vtb   = kb  + (size_t)ROWS_ * H_;              // 2MB
    unsigned short* wt    = vtb + (size_t)ROWS_ * H_;              // 384KB
    unsigned short* partO = wt  + (size_t)3*64*C_;                 // 640*8KB
    float*          partML = (float*)(partO + (size_t)640*4096);   // 640*512B

    prep_weights<<<48, 256, 0, stream>>>(wq, wk, wv, wt);
    qkv_mfma_kernel<<<ROWS_/64, 512, 0, stream>>>(x, wt, qb, kb, vtb);
    attn_chunk_kernel<<<640, 256, 0, stream>>>(qb, kb, vtb, partO, partML);
    combine_kernel<<<256, 256, 0, stream>>>(partO, partML, out);
}